// Round 3
// baseline (98.772 us; speedup 1.0000x reference)
//
#include <hip/hip_runtime.h>
#include <hip/hip_cooperative_groups.h>

namespace cg = cooperative_groups;

// PDE2DReservoir — spectral Green's function, single cooperative dispatch.
// measured[m] = sum_j vals_j * K(m - p_j); K built spectrally on a 128-periodic
// domain (support radius <= 63, so free-space == 128-periodic == 4096-periodic).

#define N_INJ   4096
#define N_MEAS  4096
#define ND      128
#define STEPS   64
#define WRAP_M  4095
#define NB      256     // blocks (1 per CU, cooperative-safe)
#define NT      256     // threads per block
#define MPB     16      // measurements per block (N_MEAS / NB)

__device__ float g_K[ND * ND];     // Green's stencil, delta at (0,0), 128-periodic
__device__ float g_B[ND * ND];     // intermediate: B[wx][y]
__device__ float g_vals[N_INJ];
__device__ int   g_pack[N_INJ];    // (ix<<12) | iy

__global__ __launch_bounds__(NT) void fused_kernel(const float* __restrict__ u_t,
                                                   const float* __restrict__ scales,
                                                   const int* __restrict__ dims,
                                                   const int* __restrict__ iix,
                                                   const int* __restrict__ iiy,
                                                   const int* __restrict__ mix,
                                                   const int* __restrict__ miy,
                                                   float* __restrict__ out) {
    cg::grid_group grid = cg::this_grid();
    const int b = blockIdx.x;
    const int t = threadIdx.x;

    __shared__ float ctab[ND];      // cos(2*pi*i/128), persists across phases
    __shared__ float coeff[STEPS];  // DT * sin(2*pi*s/64)
    __shared__ float khat[ND];

    // ---- Phase 0: Khat row b + pass-1 transform (blocks 0..127); vals (128..143)
    if (b < ND) {
        if (t < ND) {
            ctab[t] = cosf(0.049087385212340517f * (float)t);
            if (t < STEPS) coeff[t] = 0.001f * sinf(0.09817477042468103f * (float)t);
        }
        __syncthreads();
        if (t < ND) {
            const float lam = 0.9f + 0.05f * (ctab[b] + ctab[t]);
            float h = coeff[0];
#pragma unroll
            for (int s = 1; s < STEPS; ++s) h = fmaf(h, lam, coeff[s]);
            khat[t] = h;
        }
        __syncthreads();
        if (t < ND) {
            float acc = 0.f;
#pragma unroll 8
            for (int wy = 0; wy < ND; ++wy)
                acc = fmaf(khat[wy], ctab[(wy * t) & (ND - 1)], acc);
            g_B[b * ND + t] = acc;
        }
    } else if (b < ND + N_INJ / NT) {
        const int j = (b - ND) * NT + t;
        g_vals[j] = scales[j] * u_t[dims[j]];
        g_pack[j] = (iix[j] << 12) | iiy[j];
    }
    grid.sync();

    // ---- Phase 1: pass-2 transform -> g_K (blocks 0..127; ctab still in LDS)
    if (b < ND && t < ND) {
        float acc = 0.f;
#pragma unroll 8
        for (int wx = 0; wx < ND; ++wx)
            acc = fmaf(g_B[wx * ND + t], ctab[(wx * b) & (ND - 1)], acc);
        g_K[b * ND + t] = acc * (1.f / 16384.f);
    }
    grid.sync();

    // ---- Phase 2: 16 measurements per block; one shared scan of injections
    __shared__ int smx[MPB], smy[MPB];
    if (t < MPB) { smx[t] = mix[b * MPB + t]; smy[t] = miy[b * MPB + t]; }
    __syncthreads();

    float acc[MPB];
#pragma unroll
    for (int i = 0; i < MPB; ++i) acc[i] = 0.f;

#pragma unroll
    for (int jj = 0; jj < N_INJ / NT; ++jj) {
        const int j  = jj * NT + t;
        const int p  = g_pack[j];
        const float v = g_vals[j];
        const int ix = p >> 12;
        const int iy = p & WRAP_M;
#pragma unroll
        for (int i = 0; i < MPB; ++i) {
            const int a  = (smx[i] - ix) & WRAP_M;
            const int c  = (smy[i] - iy) & WRAP_M;
            const int ax = a < 2048 ? a : 4096 - a;
            const int ay = c < 2048 ? c : 4096 - c;
            if (ax < 64 && ay < 64)
                acc[i] += v * g_K[((a & (ND - 1)) << 7) + (c & (ND - 1))];
        }
    }

    // reduce 16 accumulators across 256 threads
#pragma unroll
    for (int i = 0; i < MPB; ++i) {
#pragma unroll
        for (int off = 32; off > 0; off >>= 1)
            acc[i] += __shfl_down(acc[i], off, 64);
    }
    __shared__ float part[4][MPB];
    const int lane = t & 63;
    const int wid  = t >> 6;
    if (lane == 0) {
#pragma unroll
        for (int i = 0; i < MPB; ++i) part[wid][i] = acc[i];
    }
    __syncthreads();
    if (t < MPB)
        out[b * MPB + t] = (part[0][t] + part[1][t]) + (part[2][t] + part[3][t]);
}

extern "C" void kernel_launch(void* const* d_in, const int* in_sizes, int n_in,
                              void* d_out, int out_size, void* d_ws, size_t ws_size,
                              hipStream_t stream) {
    const float* u_t        = (const float*)d_in[0];
    const float* inj_scales = (const float*)d_in[1];
    const int*   inj_dims   = (const int*)d_in[2];
    const int*   inj_ix     = (const int*)d_in[3];
    const int*   inj_iy     = (const int*)d_in[4];
    const int*   meas_ix    = (const int*)d_in[5];
    const int*   meas_iy    = (const int*)d_in[6];
    float*       out        = (float*)d_out;

    void* args[] = {(void*)&u_t, (void*)&inj_scales, (void*)&inj_dims,
                    (void*)&inj_ix, (void*)&inj_iy, (void*)&meas_ix,
                    (void*)&meas_iy, (void*)&out};
    hipLaunchCooperativeKernel((void*)fused_kernel, dim3(NB), dim3(NT),
                               args, 0, stream);
}

// Round 4
// 76.682 us; speedup vs baseline: 1.2881x; 1.2881x over previous
//
#include <hip/hip_runtime.h>

// PDE2DReservoir — spectral Green's function, 2 dispatches.
// measured[m] = sum_j vals_j * K(m - p_j);  K is a fixed 127-radius stencil
// (support << wrap), computed on a 128-periodic domain:
//   lambda(wx,wy) = 0.9 + 0.05*(cos tx + cos ty)
//   Khat = DT * sum_s f_s lambda^(63-s)       (Horner, deg 63)
//   B_T[y][wx] = (1/16384) * sum_wy Khat(wx,wy) cos(wy*y)   (pass 1, stored)
//   K(x,y)     = sum_wx B_T[y][wx] cos(wx*x)                (pass 2, on the fly
//                                                            per measurement hit)

#define N_INJ   4096
#define N_MEAS  4096
#define ND      128
#define STEPS   64
#define WRAP_M  4095
#define MPB     8                    // measurements per block
#define MB      (N_MEAS / MPB)       // 512 measure blocks

__device__ float g_BT[ND * ND];      // pass-1 output, transposed, /16384 folded
__device__ float g_vals[N_INJ];
__device__ int   g_pack[N_INJ];      // (ix<<12) | iy

// Blocks 0..127: Khat row wx=b (Horner) + pass-1 cosine transform -> g_BT.
// Blocks 128..159: vals + packed injection coords.
__global__ __launch_bounds__(128) void pass1_kernel(const float* __restrict__ u_t,
                                                    const float* __restrict__ scales,
                                                    const int* __restrict__ dims,
                                                    const int* __restrict__ iix,
                                                    const int* __restrict__ iiy) {
    const int b = blockIdx.x;
    const int t = threadIdx.x;
    if (b >= ND) {
        const int j = (b - ND) * 128 + t;       // 32 blocks * 128 = 4096
        g_vals[j] = scales[j] * u_t[dims[j]];
        g_pack[j] = (iix[j] << 12) | iiy[j];
        return;
    }
    __shared__ float ctab[ND];       // cos(2*pi*i/128)
    __shared__ float coeff[STEPS];   // DT * sin(2*pi*s/64)
    __shared__ float khat[ND];
    ctab[t] = cosf(0.049087385212340517f * (float)t);
    if (t < STEPS) coeff[t] = 0.001f * sinf(0.09817477042468103f * (float)t);
    __syncthreads();

    const float lam = 0.9f + 0.05f * (ctab[b] + ctab[t]);
    float h = coeff[0];
#pragma unroll
    for (int s = 1; s < STEPS; ++s) h = fmaf(h, lam, coeff[s]);
    khat[t] = h;                     // Khat(wx=b, wy=t)
    __syncthreads();

    float acc = 0.f;
#pragma unroll 8
    for (int wy = 0; wy < ND; ++wy)
        acc = fmaf(khat[wy], ctab[(wy * t) & (ND - 1)], acc);
    g_BT[t * ND + b] = acc * (1.f / 16384.f);   // transposed store
}

// 512 blocks x 256 threads; 8 measurements per block. Each block scans all
// 4096 injections once; a hit (|dx|,|dy| <= 63, ~2 per measurement) triggers
// the on-the-fly pass-2 dot: K(a,c) = sum_wx B_T[c][wx] * cos(wx*a).
__global__ __launch_bounds__(256) void measure_kernel(const int* __restrict__ mix,
                                                      const int* __restrict__ miy,
                                                      float* __restrict__ out) {
    const int b = blockIdx.x;
    const int t = threadIdx.x;
    __shared__ float ctab[ND];
    __shared__ int smx[MPB], smy[MPB];
    if (t < ND) ctab[t] = cosf(0.049087385212340517f * (float)t);
    if (t < MPB) { smx[t] = mix[b * MPB + t]; smy[t] = miy[b * MPB + t]; }
    __syncthreads();

    float acc[MPB];
#pragma unroll
    for (int i = 0; i < MPB; ++i) acc[i] = 0.f;

#pragma unroll
    for (int jj = 0; jj < N_INJ / 256; ++jj) {
        const int j   = jj * 256 + t;
        const int p   = g_pack[j];
        const float v = g_vals[j];
        const int ix  = p >> 12;
        const int iy  = p & WRAP_M;
#pragma unroll
        for (int i = 0; i < MPB; ++i) {
            const int a  = (smx[i] - ix) & WRAP_M;
            const int c  = (smy[i] - iy) & WRAP_M;
            const int ax = a < 2048 ? a : 4096 - a;
            const int ay = c < 2048 ? c : 4096 - c;
            if (ax < 64 && ay < 64) {
                const int am = a & (ND - 1);
                const int cm = c & (ND - 1);
                const float* __restrict__ Brow = &g_BT[cm * ND];
                float s = 0.f;
                int idx = 0;
#pragma unroll 4
                for (int wx = 0; wx < ND; ++wx) {
                    s = fmaf(Brow[wx], ctab[idx], s);
                    idx = (idx + am) & (ND - 1);
                }
                acc[i] += v * s;
            }
        }
    }

#pragma unroll
    for (int i = 0; i < MPB; ++i) {
#pragma unroll
        for (int off = 32; off > 0; off >>= 1)
            acc[i] += __shfl_down(acc[i], off, 64);
    }
    __shared__ float part[4][MPB];
    const int lane = t & 63;
    const int wid  = t >> 6;
    if (lane == 0) {
#pragma unroll
        for (int i = 0; i < MPB; ++i) part[wid][i] = acc[i];
    }
    __syncthreads();
    if (t < MPB)
        out[b * MPB + t] = (part[0][t] + part[1][t]) + (part[2][t] + part[3][t]);
}

extern "C" void kernel_launch(void* const* d_in, const int* in_sizes, int n_in,
                              void* d_out, int out_size, void* d_ws, size_t ws_size,
                              hipStream_t stream) {
    const float* u_t        = (const float*)d_in[0];
    const float* inj_scales = (const float*)d_in[1];
    const int*   inj_dims   = (const int*)d_in[2];
    const int*   inj_ix     = (const int*)d_in[3];
    const int*   inj_iy     = (const int*)d_in[4];
    const int*   meas_ix    = (const int*)d_in[5];
    const int*   meas_iy    = (const int*)d_in[6];
    float*       out        = (float*)d_out;

    hipLaunchKernelGGL(pass1_kernel, dim3(ND + N_INJ / 128), dim3(128), 0, stream,
                       u_t, inj_scales, inj_dims, inj_ix, inj_iy);
    hipLaunchKernelGGL(measure_kernel, dim3(MB), dim3(256), 0, stream,
                       meas_ix, meas_iy, out);
}

// Round 5
// 55.464 us; speedup vs baseline: 1.7808x; 1.3825x over previous
//
#include <hip/hip_runtime.h>

// PDE2DReservoir — spectral Green's function, SINGLE dispatch with a
// hand-rolled grid barrier.
// measured[m] = sum_j vals_j * K(m - p_j); K is a fixed 127-radius stencil
// computed on a 128-periodic domain via folded cosine modes (wx,wy in 0..64):
//   lambda = 0.9 + 0.05*(cos wx + cos wy);  Khat = DT * sum_s f_s lambda^(63-s)
//   K(x,y) = sum_wx sum_wy W(wx)W(wy)/16384 * Khat * cos(wx x) cos(wy y)
// Each K-row block is self-contained (own Horner table) -> no inter-block
// dependency until the single barrier; then all blocks gather measurements.

#define N_INJ   4096
#define N_MEAS  4096
#define ND      128
#define NM      65              // folded modes 0..64
#define STEPS   64
#define WRAP_M  4095
#define NB      256             // grid blocks (all co-resident: <=18KB LDS, 256 thr)
#define NT      256
#define MPB     16              // measurements per block

__device__ float    g_K[ND * ND];
__device__ float    g_vals[N_INJ];
__device__ int      g_pack[N_INJ];
__device__ unsigned g_bar = 0;   // monotonic arrive counter (replay-safe, no reset)

__global__ __launch_bounds__(NT) void fused(const float* __restrict__ u_t,
                                            const float* __restrict__ scales,
                                            const int* __restrict__ dims,
                                            const int* __restrict__ iix,
                                            const int* __restrict__ iiy,
                                            const int* __restrict__ mix,
                                            const int* __restrict__ miy,
                                            float* __restrict__ out) {
    const int b = blockIdx.x;
    const int t = threadIdx.x;

    __shared__ float ctab[ND];        // cos(2*pi*i/128)
    __shared__ float coeff[STEPS];    // DT * sin(2*pi*s/64)
    __shared__ float khf[NM * NM];    // weighted Khat, flat wx*65+wy (16.9 KB)
    __shared__ float Cw[NM];
    __shared__ int   smx[MPB], smy[MPB];
    __shared__ float part[4][MPB];

    // ---------------- Phase A: build (blocks 0..127: K row x=b) ----------------
    if (b < ND) {
        if (t < ND)    ctab[t]  = cosf(0.049087385212340517f * (float)t);
        if (t < STEPS) coeff[t] = 0.001f * sinf(0.09817477042468103f * (float)t);
        __syncthreads();

        // Horner over 17 table entries per thread: e = t + 256k
        float h[17], lam[17];
#pragma unroll
        for (int k = 0; k < 17; ++k) {
            int e = t + 256 * k; if (e > NM * NM - 1) e = NM * NM - 1;
            const int wx = e / NM, wy = e - wx * NM;
            lam[k] = 0.9f + 0.05f * (ctab[wx] + ctab[wy]);
            h[k]   = coeff[0];
        }
        for (int s = 1; s < STEPS; ++s) {
            const float cs = coeff[s];
#pragma unroll
            for (int k = 0; k < 17; ++k) h[k] = fmaf(h[k], lam[k], cs);
        }
#pragma unroll
        for (int k = 0; k < 17; ++k) {
            const int e = t + 256 * k;
            if (e < NM * NM) {
                const int wx = e / NM, wy = e - wx * NM;
                const float w = ((wx == 0 || wx == 64) ? 1.f : 2.f)
                              * ((wy == 0 || wy == 64) ? 1.f : 2.f) * (1.f / 16384.f);
                khf[e] = h[k] * w;
            }
        }
        __syncthreads();

        // Cw[wy] = sum_wx khf[wx][wy] * cos(wx * x)
        if (t < NM) {
            float acc = 0.f; int idx = 0;
#pragma unroll 5
            for (int wx = 0; wx < NM; ++wx) {
                acc = fmaf(khf[wx * NM + t], ctab[idx], acc);
                idx = (idx + b) & (ND - 1);
            }
            Cw[t] = acc;
        }
        __syncthreads();

        // K(x=b, y=t) = sum_wy Cw[wy] * cos(wy * y)
        if (t < ND) {
            float acc = 0.f; int idx = 0;
#pragma unroll 5
            for (int wy = 0; wy < NM; ++wy) {
                acc = fmaf(Cw[wy], ctab[idx], acc);
                idx = (idx + t) & (ND - 1);
            }
            g_K[b * ND + t] = acc;
        }
    } else if (b < ND + N_INJ / NT) {   // blocks 128..143: vals + packed coords
        const int j = (b - ND) * NT + t;
        g_vals[j] = scales[j] * u_t[dims[j]];
        g_pack[j] = (iix[j] << 12) | iiy[j];
    }

    // ---------------- Grid barrier (replay-safe, no reset) ----------------
    __threadfence();                     // release our writes device-wide
    __syncthreads();
    if (t == 0) {
        const unsigned old    = atomicAdd(&g_bar, 1u);        // device scope
        const unsigned target = (old & ~(unsigned)(NB - 1)) + NB;
        while ((int)(__hip_atomic_load(&g_bar, __ATOMIC_RELAXED,
                                       __HIP_MEMORY_SCOPE_AGENT) - target) < 0)
            __builtin_amdgcn_s_sleep(2);
        __threadfence();                 // acquire: invalidate caches
    }
    __syncthreads();

    // ---------------- Phase B: measure (all 256 blocks, 16 each) ----------------
    if (t < MPB) { smx[t] = mix[b * MPB + t]; smy[t] = miy[b * MPB + t]; }
    __syncthreads();

    float acc[MPB];
#pragma unroll
    for (int i = 0; i < MPB; ++i) acc[i] = 0.f;

#pragma unroll
    for (int jj = 0; jj < N_INJ / NT; ++jj) {
        const int j   = jj * NT + t;
        const int p   = g_pack[j];
        const float v = g_vals[j];
        const int ix  = p >> 12;
        const int iy  = p & WRAP_M;
#pragma unroll
        for (int i = 0; i < MPB; ++i) {
            const int a  = (smx[i] - ix) & WRAP_M;
            const int c  = (smy[i] - iy) & WRAP_M;
            const int ax = a < 2048 ? a : 4096 - a;
            const int ay = c < 2048 ? c : 4096 - c;
            if (ax < 64 && ay < 64)
                acc[i] += v * g_K[((a & (ND - 1)) << 7) + (c & (ND - 1))];
        }
    }

#pragma unroll
    for (int i = 0; i < MPB; ++i) {
#pragma unroll
        for (int off = 32; off > 0; off >>= 1)
            acc[i] += __shfl_down(acc[i], off, 64);
    }
    const int lane = t & 63;
    const int wid  = t >> 6;
    if (lane == 0) {
#pragma unroll
        for (int i = 0; i < MPB; ++i) part[wid][i] = acc[i];
    }
    __syncthreads();
    if (t < MPB)
        out[b * MPB + t] = (part[0][t] + part[1][t]) + (part[2][t] + part[3][t]);
}

extern "C" void kernel_launch(void* const* d_in, const int* in_sizes, int n_in,
                              void* d_out, int out_size, void* d_ws, size_t ws_size,
                              hipStream_t stream) {
    const float* u_t        = (const float*)d_in[0];
    const float* inj_scales = (const float*)d_in[1];
    const int*   inj_dims   = (const int*)d_in[2];
    const int*   inj_ix     = (const int*)d_in[3];
    const int*   inj_iy     = (const int*)d_in[4];
    const int*   meas_ix    = (const int*)d_in[5];
    const int*   meas_iy    = (const int*)d_in[6];
    float*       out        = (float*)d_out;

    hipLaunchKernelGGL(fused, dim3(NB), dim3(NT), 0, stream,
                       u_t, inj_scales, inj_dims, inj_ix, inj_iy,
                       meas_ix, meas_iy, out);
}